// Round 1
// baseline (4405.293 us; speedup 1.0000x reference)
//
#include <hip/hip_runtime.h>
#include <hip/hip_bf16.h>
#include <stdint.h>
#include <stddef.h>

// tidigitsRNNPT: Elman RNN (B=128, SEQ=254, FEAT=39, HID=1024) -> FC1(260096->100)+ReLU -> FC2(100->10) -> log_softmax
//
// Plan:
//  k1: convert W_hh -> bf16 (register-resident in scan), h0 -> bf16
//  k2: xproj[s][b][h] = x[b,s,:]@W_ih[h,:] + b_ih[h] + b_hh[h]   (bf16, 66.6MB ws)
//  k3: persistent scan kernel, 128 blocks x 256thr, custom grid barrier per step.
//      wave owns [16b x 16h] MFMA tile; W_hh slice lives in 128 VGPRs (short8 breg[32]).
//      writes h (double-buffered, cross-block) and outs[s][b][h] (bf16, for FC1).
//  k4: FC1 via MFMA: per-s blocks compute [128b x 112j] partials (W1 converted to bf16 on the fly)
//  k5: reduce partials over s + bias + relu + FC2 + log_softmax

typedef unsigned short u16;
typedef __attribute__((ext_vector_type(4))) float f32x4;
typedef __attribute__((ext_vector_type(4))) unsigned short u16x4;
typedef __attribute__((ext_vector_type(8))) short short8;

#define SEQ   254
#define BATCH 128
#define HID   1024
#define FEAT  39
#define FC1N  100
#define FC1P  112   // 7*16, padded
#define NCLS  10
#define NBLK_SCAN 128

// ---- workspace layout (all offsets 256B aligned) ----
#define OFF_CNT   ((size_t)0)
#define OFF_HBUF  ((size_t)256)                                   // 2 * 128*1024 bf16 = 524288
#define OFF_WHH   (OFF_HBUF + (size_t)2*BATCH*HID*2)              // 1024*1024 bf16 = 2097152
#define OFF_XP    (OFF_WHH + (size_t)HID*HID*2)                   // 254*128*1024 bf16
#define OFF_OUTS  (OFF_XP + (size_t)SEQ*BATCH*HID*2)
#define OFF_PART  (OFF_OUTS + (size_t)SEQ*BATCH*HID*2)            // 254*128*112 f32
#define WS_NEED   (OFF_PART + (size_t)SEQ*BATCH*FC1P*4)

__device__ inline u16 f2bf(float f){
  union { float f; unsigned u; } v; v.f = f;
  unsigned u = v.u;
  u += 0x7fffu + ((u >> 16) & 1u);      // round-to-nearest-even
  return (u16)(u >> 16);
}
__device__ inline float bf2f(u16 h){
  union { unsigned u; float f; } v; v.u = ((unsigned)h) << 16;
  return v.f;
}
__device__ inline float fast_tanh(float x){
  // tanh(x) = 1 - 2/(exp(2x)+1); stable at both tails (e->inf => 1, e->0 => -1)
  float e = __expf(2.0f * x);
  return 1.0f - 2.0f / (e + 1.0f);
}

// ---------------- fp32 -> bf16 bulk convert ----------------
__global__ void cvt_f32_bf16_kernel(const float* __restrict__ in, u16* __restrict__ out, int n4){
  int i = blockIdx.x * blockDim.x + threadIdx.x;
  if (i < n4){
    f32x4 v = *(const f32x4*)(in + (size_t)i * 4);
    u16x4 o;
    o[0] = f2bf(v[0]); o[1] = f2bf(v[1]); o[2] = f2bf(v[2]); o[3] = f2bf(v[3]);
    *(u16x4*)(out + (size_t)i * 4) = o;
  }
}

// ---------------- xproj: [SEQ][BATCH][HID] bf16 ----------------
__global__ __launch_bounds__(1024) void xproj_kernel(const float* __restrict__ x,
                                                     const float* __restrict__ W_ih,
                                                     const float* __restrict__ b_ih,
                                                     const float* __restrict__ b_hh,
                                                     u16* __restrict__ xp){
  const int s = blockIdx.x;
  __shared__ float xs[BATCH * (FEAT + 1)];
  for (int i = threadIdx.x; i < BATCH * FEAT; i += 1024){
    int b = i / FEAT, f = i - b * FEAT;
    xs[b * (FEAT + 1) + f] = x[((size_t)b * SEQ + s) * FEAT + f];
  }
  __syncthreads();
  const int h = threadIdx.x;
  float w[FEAT];
  #pragma unroll
  for (int f = 0; f < FEAT; ++f) w[f] = W_ih[h * FEAT + f];
  const float bias = b_ih[h] + b_hh[h];
  for (int b = 0; b < BATCH; ++b){
    float acc = bias;
    #pragma unroll
    for (int f = 0; f < FEAT; ++f) acc += xs[b * (FEAT + 1) + f] * w[f];
    xp[((size_t)s * BATCH + b) * HID + h] = f2bf(acc);
  }
}

// ---------------- persistent RNN scan ----------------
// 128 blocks co-resident on 256 CUs (residency guaranteed) -> custom barrier is deadlock-free.
__global__ __launch_bounds__(256, 1) void scan_kernel(const u16* __restrict__ whh,
                                                      const u16* __restrict__ xp,
                                                      u16* __restrict__ hbuf,
                                                      u16* __restrict__ outs,
                                                      int* cnt){
  const int bid  = blockIdx.x;
  const int bgrp = bid & 7;           // 8 groups of 16 batches
  const int hgrp = bid >> 3;          // 16 groups of 64 hidden
  const int wid  = threadIdx.x >> 6;
  const int lane = threadIdx.x & 63;
  const int lr = lane & 15;           // row-in-tile
  const int lg = lane >> 4;           // k-group
  const int b_base = bgrp * 16;
  const int h_base = hgrp * 64 + wid * 16;

  // W_hh slice for this wave, register-resident: breg[kk] = W[h_base+lr][kk*32 + lg*8 .. +7]
  short8 breg[32];
  {
    const u16* wp = whh + (size_t)(h_base + lr) * HID + lg * 8;
    #pragma unroll
    for (int kk = 0; kk < 32; ++kk) breg[kk] = *(const short8*)(wp + kk * 32);
  }

  const int arow  = (b_base + lr) * HID + lg * 8;
  const int b_out = b_base + lg * 4;       // + r (C/D: row=(lane>>4)*4+reg)
  const int h_out = h_base + lr;           // (C/D: col=lane&15)
  const int nblk  = (int)gridDim.x;

  for (int s = 0; s < SEQ; ++s){
    const u16* hcur = hbuf + (size_t)(s & 1) * (BATCH * HID);
    u16*       hnxt = hbuf + (size_t)((s & 1) ^ 1) * (BATCH * HID);

    // acc init from xproj (includes both biases)
    const u16* xpp = xp + ((size_t)s * BATCH + b_out) * HID + h_out;
    f32x4 acc;
    acc[0] = bf2f(xpp[0]);
    acc[1] = bf2f(xpp[HID]);
    acc[2] = bf2f(xpp[2 * HID]);
    acc[3] = bf2f(xpp[3 * HID]);

    const u16* pa = hcur + arow;
    #pragma unroll
    for (int kk = 0; kk < 32; ++kk){
      short8 a = *(const short8*)(pa + kk * 32);
      acc = __builtin_amdgcn_mfma_f32_16x16x32_bf16(a, breg[kk], acc, 0, 0, 0);
    }

    u16* op = outs + ((size_t)s * BATCH + b_out) * HID + h_out;
    u16* hp = hnxt + (size_t)b_out * HID + h_out;
    #pragma unroll
    for (int r = 0; r < 4; ++r){
      u16 uv = f2bf(fast_tanh(acc[r]));
      hp[r * HID] = uv;
      op[r * HID] = uv;
    }

    // ---- grid barrier (monotonic counter, leader spin) ----
    __syncthreads();
    if (threadIdx.x == 0){
      __threadfence();
      __hip_atomic_fetch_add(cnt, 1, __ATOMIC_ACQ_REL, __HIP_MEMORY_SCOPE_AGENT);
      const int tgt = (s + 1) * nblk;
      while (__hip_atomic_load(cnt, __ATOMIC_ACQUIRE, __HIP_MEMORY_SCOPE_AGENT) < tgt){
        __builtin_amdgcn_s_sleep(1);
      }
      __threadfence();
    }
    __syncthreads();
  }
}

// ---------------- FC1 partials via MFMA ----------------
// block = one timestep s (254 blocks, 4 waves). wave wid covers b rows [32*wid, 32*wid+32).
// n-tiles 0..6 cover j 0..111 (j>=100 zero-padded). W1 fp32 converted to bf16 in-flight.
__global__ __launch_bounds__(256) void fc1_kernel(const u16* __restrict__ outs,
                                                  const float* __restrict__ W1,
                                                  float* __restrict__ part){
  const int s = blockIdx.x;
  const int wid  = threadIdx.x >> 6;
  const int lane = threadIdx.x & 63;
  const int lr = lane & 15;
  const int lg = lane >> 4;

  f32x4 acc[2][7];
  const f32x4 zero = {0.f, 0.f, 0.f, 0.f};
  #pragma unroll
  for (int i = 0; i < 2; ++i)
    #pragma unroll
    for (int n = 0; n < 7; ++n) acc[i][n] = zero;

  const u16* pa0 = outs + ((size_t)s * BATCH + wid * 32 + lr) * HID + lg * 8;
  const u16* pa1 = pa0 + 16 * HID;

  for (int kk = 0; kk < 32; ++kk){
    short8 a0 = *(const short8*)(pa0 + kk * 32);
    short8 a1 = *(const short8*)(pa1 + kk * 32);
    #pragma unroll
    for (int nt = 0; nt < 7; ++nt){
      const int j = nt * 16 + lr;
      short8 bf;
      if (j < FC1N){
        const float* wp = W1 + (size_t)j * (SEQ * HID) + (size_t)s * HID + kk * 32 + lg * 8;
        f32x4 w0 = *(const f32x4*)wp;
        f32x4 w1 = *(const f32x4*)(wp + 4);
        #pragma unroll
        for (int r = 0; r < 4; ++r){ bf[r] = (short)f2bf(w0[r]); bf[r + 4] = (short)f2bf(w1[r]); }
      } else {
        #pragma unroll
        for (int r = 0; r < 8; ++r) bf[r] = 0;
      }
      acc[0][nt] = __builtin_amdgcn_mfma_f32_16x16x32_bf16(a0, bf, acc[0][nt], 0, 0, 0);
      acc[1][nt] = __builtin_amdgcn_mfma_f32_16x16x32_bf16(a1, bf, acc[1][nt], 0, 0, 0);
    }
  }

  #pragma unroll
  for (int i = 0; i < 2; ++i)
    #pragma unroll
    for (int nt = 0; nt < 7; ++nt)
      #pragma unroll
      for (int r = 0; r < 4; ++r){
        const int b = wid * 32 + i * 16 + lg * 4 + r;
        const int j = nt * 16 + lr;
        part[((size_t)s * BATCH + b) * FC1P + j] = acc[i][nt][r];
      }
}

// ---------------- reduce partials + bias + relu + FC2 + log_softmax ----------------
__global__ __launch_bounds__(128) void reduce_kernel(const float* __restrict__ part,
                                                     const float* __restrict__ b1,
                                                     const float* __restrict__ W2,
                                                     const float* __restrict__ b2,
                                                     float* __restrict__ out){
  const int b = blockIdx.x;
  const int j = threadIdx.x;
  __shared__ float h1[FC1N];
  __shared__ float lg[NCLS];

  if (j < FC1P){
    const float* p = part + (size_t)b * FC1P + j;
    float acc = 0.f;
    #pragma unroll 4
    for (int s = 0; s < SEQ; ++s) acc += p[(size_t)s * BATCH * FC1P];
    if (j < FC1N) h1[j] = fmaxf(acc + b1[j], 0.f);
  }
  __syncthreads();
  if (j < NCLS){
    float v = b2[j];
    for (int q = 0; q < FC1N; ++q) v += h1[q] * W2[j * FC1N + q];
    lg[j] = v;
  }
  __syncthreads();
  if (j < NCLS){
    float m = lg[0];
    #pragma unroll
    for (int q = 1; q < NCLS; ++q) m = fmaxf(m, lg[q]);
    float sum = 0.f;
    #pragma unroll
    for (int q = 0; q < NCLS; ++q) sum += __expf(lg[q] - m);
    out[b * NCLS + j] = lg[j] - (m + __logf(sum));
  }
}

extern "C" void kernel_launch(void* const* d_in, const int* in_sizes, int n_in,
                              void* d_out, int out_size, void* d_ws, size_t ws_size,
                              hipStream_t stream){
  (void)in_sizes; (void)n_in; (void)out_size; (void)ws_size;
  const float* x   = (const float*)d_in[0];
  const float* h0  = (const float*)d_in[1];
  const float* Wih = (const float*)d_in[2];
  const float* Whh = (const float*)d_in[3];
  const float* bih = (const float*)d_in[4];
  const float* bhh = (const float*)d_in[5];
  const float* W1  = (const float*)d_in[6];
  const float* b1  = (const float*)d_in[7];
  const float* W2  = (const float*)d_in[8];
  const float* b2  = (const float*)d_in[9];
  float* out = (float*)d_out;

  char* ws = (char*)d_ws;
  int*  cnt  = (int*)(ws + OFF_CNT);
  u16*  hbuf = (u16*)(ws + OFF_HBUF);
  u16*  whh  = (u16*)(ws + OFF_WHH);
  u16*  xp   = (u16*)(ws + OFF_XP);
  u16*  outs = (u16*)(ws + OFF_OUTS);
  float* part = (float*)(ws + OFF_PART);

  hipMemsetAsync(cnt, 0, 256, stream);
  cvt_f32_bf16_kernel<<<1024, 256, 0, stream>>>(Whh, whh, (HID * HID) / 4);
  cvt_f32_bf16_kernel<<<128, 256, 0, stream>>>(h0, hbuf, (BATCH * HID) / 4);
  xproj_kernel<<<SEQ, 1024, 0, stream>>>(x, Wih, bih, bhh, xp);
  scan_kernel<<<NBLK_SCAN, 256, 0, stream>>>(whh, xp, hbuf, outs, cnt);
  fc1_kernel<<<SEQ, 256, 0, stream>>>(outs, W1, part);
  reduce_kernel<<<BATCH, 128, 0, stream>>>(part, b1, W2, b2, out);
}

// Round 2
// 1718.936 us; speedup vs baseline: 2.5628x; 2.5628x over previous
//
#include <hip/hip_runtime.h>
#include <hip/hip_bf16.h>
#include <stdint.h>
#include <stddef.h>

// tidigitsRNNPT: Elman RNN (B=128, SEQ=254, FEAT=39, HID=1024) -> FC1(260096->100)+ReLU -> FC2(100->10) -> log_softmax
//
// R1: scan barrier rework. R0 post-mortem: 16.1us/step, all in the contended
// single-counter barrier + threadfence L2 invalidates.
//  - all cross-block h traffic via sc0 sc1 (IF-coherent, bypass L1/L2) -> no fences
//  - distributed per-block flags, group fan-in 16 (batch groups independent)
//  - h written once into outs slices (no slice reuse -> no WAR hazard, RAW-only sync)

typedef unsigned short u16;
typedef __attribute__((ext_vector_type(4))) float f32x4;
typedef __attribute__((ext_vector_type(4))) unsigned short u16x4;
typedef __attribute__((ext_vector_type(8))) short short8;

#define SEQ   254
#define BATCH 128
#define HID   1024
#define FEAT  39
#define FC1N  100
#define FC1P  112   // 7*16, padded
#define NCLS  10
#define NBLK_SCAN 128

// ---- workspace layout ----
// flags: 128 slots x 256B (own cacheline each)
#define OFF_FLAGS ((size_t)0)
#define OFF_HS    ((size_t)(32 * 1024))                            // (SEQ+1)*128*1024 bf16 = 66.8MB
#define OFF_WHH   (OFF_HS + (size_t)(SEQ + 1) * BATCH * HID * 2)   // 2MB
#define OFF_XP    (OFF_WHH + (size_t)HID * HID * 2)                // 66.6MB
#define OFF_PART  (OFF_XP + (size_t)SEQ * BATCH * HID * 2)         // 14.6MB

__device__ inline u16 f2bf(float f){
  union { float f; unsigned u; } v; v.f = f;
  unsigned u = v.u;
  u += 0x7fffu + ((u >> 16) & 1u);      // round-to-nearest-even
  return (u16)(u >> 16);
}
__device__ inline float bf2f(u16 h){
  union { unsigned u; float f; } v; v.u = ((unsigned)h) << 16;
  return v.f;
}
__device__ inline float fast_tanh(float x){
  float e = __expf(2.0f * x);
  return 1.0f - 2.0f / (e + 1.0f);
}

// ---- IF-coherent (cross-XCD) memory ops: sc0 sc1 bypasses L1+L2, served by Infinity Cache ----
__device__ inline short8 ld_cohx4(const u16* p){
  short8 r;
  asm volatile("global_load_dwordx4 %0, %1, off sc0 sc1" : "=v"(r) : "v"(p) : "memory");
  return r;
}
__device__ inline void st_coh_u16(u16* p, unsigned v){
  asm volatile("global_store_short %0, %1, off sc0 sc1" :: "v"(p), "v"(v) : "memory");
}
__device__ inline void st_coh_i32(int* p, int v){
  asm volatile("global_store_dword %0, %1, off sc0 sc1" :: "v"(p), "v"(v) : "memory");
}
__device__ inline int ld_coh_i32(const int* p){
  int r;
  asm volatile("global_load_dword %0, %1, off sc0 sc1\n\ts_waitcnt vmcnt(0)"
               : "=v"(r) : "v"(p) : "memory");
  return r;
}

// ---------------- fp32 -> bf16 bulk convert ----------------
__global__ void cvt_f32_bf16_kernel(const float* __restrict__ in, u16* __restrict__ out, int n4){
  int i = blockIdx.x * blockDim.x + threadIdx.x;
  if (i < n4){
    f32x4 v = *(const f32x4*)(in + (size_t)i * 4);
    u16x4 o;
    o[0] = f2bf(v[0]); o[1] = f2bf(v[1]); o[2] = f2bf(v[2]); o[3] = f2bf(v[3]);
    *(u16x4*)(out + (size_t)i * 4) = o;
  }
}

// ---------------- xproj: [SEQ][BATCH][HID] bf16 (includes both biases) ----------------
__global__ __launch_bounds__(1024) void xproj_kernel(const float* __restrict__ x,
                                                     const float* __restrict__ W_ih,
                                                     const float* __restrict__ b_ih,
                                                     const float* __restrict__ b_hh,
                                                     u16* __restrict__ xp){
  const int s = blockIdx.x;
  __shared__ float xs[BATCH * (FEAT + 1)];
  for (int i = threadIdx.x; i < BATCH * FEAT; i += 1024){
    int b = i / FEAT, f = i - b * FEAT;
    xs[b * (FEAT + 1) + f] = x[((size_t)b * SEQ + s) * FEAT + f];
  }
  __syncthreads();
  const int h = threadIdx.x;
  float w[FEAT];
  #pragma unroll
  for (int f = 0; f < FEAT; ++f) w[f] = W_ih[h * FEAT + f];
  const float bias = b_ih[h] + b_hh[h];
  for (int b = 0; b < BATCH; ++b){
    float acc = bias;
    #pragma unroll
    for (int f = 0; f < FEAT; ++f) acc += xs[b * (FEAT + 1) + f] * w[f];
    xp[((size_t)s * BATCH + b) * HID + h] = f2bf(acc);
  }
}

// ---------------- persistent RNN scan ----------------
// 128 blocks (<=256 CUs, co-resident). Block (bgrp=bid&7, hgrp=bid>>3) computes
// h[16 batches of bgrp][64 hid of hgrp]. Only the 16 blocks sharing bgrp exchange
// data -> per-group flag barrier, fan-in 16. h slices: hs[s+1] written at step s,
// never reused -> RAW-only ordering, groups may drift.
__global__ __launch_bounds__(256, 1) void scan_kernel(const u16* __restrict__ whh,
                                                      const u16* __restrict__ xp,
                                                      u16* __restrict__ hs,
                                                      int* __restrict__ flags){
  const int bid  = blockIdx.x;
  const int bgrp = bid & 7;           // 8 batch groups of 16
  const int hgrp = bid >> 3;          // 16 hid groups of 64
  const int wid  = threadIdx.x >> 6;
  const int lane = threadIdx.x & 63;
  const int lr = lane & 15;
  const int lg = lane >> 4;
  const int b_base = bgrp * 16;
  const int h_base = hgrp * 64 + wid * 16;

  // W_hh slice, register-resident: breg[kk] = W[h_base+lr][kk*32 + lg*8 .. +7]
  short8 breg[32];
  {
    const u16* wp = whh + (size_t)(h_base + lr) * HID + lg * 8;
    #pragma unroll
    for (int kk = 0; kk < 32; ++kk) breg[kk] = *(const short8*)(wp + kk * 32);
  }

  const int arow  = (b_base + lr) * HID + lg * 8;
  const int b_out = b_base + lg * 4;       // + r (C/D: row=(lane>>4)*4+reg)
  const int h_out = h_base + lr;           // (C/D: col=lane&15)

  int* flag_self = flags + (hgrp * 8 + bgrp) * 64;
  const int* flag_peer = (threadIdx.x < 16) ? (flags + (threadIdx.x * 8 + bgrp) * 64) : flags;

  for (int s = 0; s < SEQ; ++s){
    const u16* hcur = hs + (size_t)s * (BATCH * HID);

    // issue all 32 A-fragment loads (IF-coherent), then one wait
    short8 a[32];
    const u16* pa = hcur + arow;
    #pragma unroll
    for (int kk = 0; kk < 32; ++kk) a[kk] = ld_cohx4(pa + kk * 32);

    // acc init from xproj (cached load, read-only data)
    const u16* xpp = xp + ((size_t)s * BATCH + b_out) * HID + h_out;
    f32x4 acc;
    acc[0] = bf2f(xpp[0]);
    acc[1] = bf2f(xpp[HID]);
    acc[2] = bf2f(xpp[2 * HID]);
    acc[3] = bf2f(xpp[3 * HID]);

    asm volatile("s_waitcnt vmcnt(0)" ::: "memory");
    __builtin_amdgcn_sched_barrier(0);

    #pragma unroll
    for (int kk = 0; kk < 32; ++kk)
      acc = __builtin_amdgcn_mfma_f32_16x16x32_bf16(a[kk], breg[kk], acc, 0, 0, 0);

    // tanh -> bf16 -> store into slice s+1 (write-once; also consumed by fc1)
    u16* hp = hs + (size_t)(s + 1) * (BATCH * HID) + (size_t)b_out * HID + h_out;
    #pragma unroll
    for (int r = 0; r < 4; ++r)
      st_coh_u16(hp + r * HID, (unsigned)f2bf(fast_tanh(acc[r])));

    asm volatile("s_waitcnt vmcnt(0)" ::: "memory");   // drain own h stores
    __syncthreads();                                    // whole block drained
    if (threadIdx.x == 0) st_coh_i32(flag_self, s + 1); // release (own cacheline)
    if (threadIdx.x < 16){                              // await 16 group peers
      while (ld_coh_i32(flag_peer) <= s) __builtin_amdgcn_s_sleep(2);
    }
    __syncthreads();
  }
}

// ---------------- FC1 partials via MFMA ----------------
__global__ __launch_bounds__(256) void fc1_kernel(const u16* __restrict__ outs,
                                                  const float* __restrict__ W1,
                                                  float* __restrict__ part){
  const int s = blockIdx.x;
  const int wid  = threadIdx.x >> 6;
  const int lane = threadIdx.x & 63;
  const int lr = lane & 15;
  const int lg = lane >> 4;

  f32x4 acc[2][7];
  const f32x4 zero = {0.f, 0.f, 0.f, 0.f};
  #pragma unroll
  for (int i = 0; i < 2; ++i)
    #pragma unroll
    for (int n = 0; n < 7; ++n) acc[i][n] = zero;

  const u16* pa0 = outs + ((size_t)s * BATCH + wid * 32 + lr) * HID + lg * 8;
  const u16* pa1 = pa0 + 16 * HID;

  for (int kk = 0; kk < 32; ++kk){
    short8 a0 = *(const short8*)(pa0 + kk * 32);
    short8 a1 = *(const short8*)(pa1 + kk * 32);
    #pragma unroll
    for (int nt = 0; nt < 7; ++nt){
      const int j = nt * 16 + lr;
      short8 bf;
      if (j < FC1N){
        const float* wp = W1 + (size_t)j * (SEQ * HID) + (size_t)s * HID + kk * 32 + lg * 8;
        f32x4 w0 = *(const f32x4*)wp;
        f32x4 w1 = *(const f32x4*)(wp + 4);
        #pragma unroll
        for (int r = 0; r < 4; ++r){ bf[r] = (short)f2bf(w0[r]); bf[r + 4] = (short)f2bf(w1[r]); }
      } else {
        #pragma unroll
        for (int r = 0; r < 8; ++r) bf[r] = 0;
      }
      acc[0][nt] = __builtin_amdgcn_mfma_f32_16x16x32_bf16(a0, bf, acc[0][nt], 0, 0, 0);
      acc[1][nt] = __builtin_amdgcn_mfma_f32_16x16x32_bf16(a1, bf, acc[1][nt], 0, 0, 0);
    }
  }

  #pragma unroll
  for (int i = 0; i < 2; ++i)
    #pragma unroll
    for (int nt = 0; nt < 7; ++nt)
      #pragma unroll
      for (int r = 0; r < 4; ++r){
        const int b = wid * 32 + i * 16 + lg * 4 + r;
        const int j = nt * 16 + lr;
        part[((size_t)s * BATCH + b) * FC1P + j] = acc[i][nt][r];
      }
}

// ---------------- reduce partials + bias + relu + FC2 + log_softmax ----------------
__global__ __launch_bounds__(128) void reduce_kernel(const float* __restrict__ part,
                                                     const float* __restrict__ b1,
                                                     const float* __restrict__ W2,
                                                     const float* __restrict__ b2,
                                                     float* __restrict__ out){
  const int b = blockIdx.x;
  const int j = threadIdx.x;
  __shared__ float h1[FC1N];
  __shared__ float lgt[NCLS];

  if (j < FC1P){
    const float* p = part + (size_t)b * FC1P + j;
    float acc = 0.f;
    #pragma unroll 4
    for (int s = 0; s < SEQ; ++s) acc += p[(size_t)s * BATCH * FC1P];
    if (j < FC1N) h1[j] = fmaxf(acc + b1[j], 0.f);
  }
  __syncthreads();
  if (j < NCLS){
    float v = b2[j];
    for (int q = 0; q < FC1N; ++q) v += h1[q] * W2[j * FC1N + q];
    lgt[j] = v;
  }
  __syncthreads();
  if (j < NCLS){
    float m = lgt[0];
    #pragma unroll
    for (int q = 1; q < NCLS; ++q) m = fmaxf(m, lgt[q]);
    float sum = 0.f;
    #pragma unroll
    for (int q = 0; q < NCLS; ++q) sum += __expf(lgt[q] - m);
    out[b * NCLS + j] = lgt[j] - (m + __logf(sum));
  }
}

extern "C" void kernel_launch(void* const* d_in, const int* in_sizes, int n_in,
                              void* d_out, int out_size, void* d_ws, size_t ws_size,
                              hipStream_t stream){
  (void)in_sizes; (void)n_in; (void)out_size; (void)ws_size;
  const float* x   = (const float*)d_in[0];
  const float* h0  = (const float*)d_in[1];
  const float* Wih = (const float*)d_in[2];
  const float* Whh = (const float*)d_in[3];
  const float* bih = (const float*)d_in[4];
  const float* bhh = (const float*)d_in[5];
  const float* W1  = (const float*)d_in[6];
  const float* b1  = (const float*)d_in[7];
  const float* W2  = (const float*)d_in[8];
  const float* b2  = (const float*)d_in[9];
  float* out = (float*)d_out;

  char* ws = (char*)d_ws;
  int*  flags = (int*)(ws + OFF_FLAGS);
  u16*  hs    = (u16*)(ws + OFF_HS);
  u16*  whh   = (u16*)(ws + OFF_WHH);
  u16*  xp    = (u16*)(ws + OFF_XP);
  float* part = (float*)(ws + OFF_PART);

  hipMemsetAsync(flags, 0, 32 * 1024, stream);
  cvt_f32_bf16_kernel<<<1024, 256, 0, stream>>>(Whh, whh, (HID * HID) / 4);
  cvt_f32_bf16_kernel<<<128, 256, 0, stream>>>(h0, hs, (BATCH * HID) / 4);
  xproj_kernel<<<SEQ, 1024, 0, stream>>>(x, Wih, bih, bhh, xp);
  scan_kernel<<<NBLK_SCAN, 256, 0, stream>>>(whh, xp, hs, flags);
  fc1_kernel<<<SEQ, 256, 0, stream>>>(hs + (size_t)BATCH * HID, W1, part);
  reduce_kernel<<<BATCH, 128, 0, stream>>>(part, b1, W2, b2, out);
}